// Round 8
// baseline (489.541 us; speedup 1.0000x reference)
//
#include <hip/hip_runtime.h>
#include <hip/hip_bf16.h>

// Sizes (fixed by the reference)
#define BATCH 8192
#define DIM   128
#define NPAT  64
#define VOCAB 32000

// GEMM geometry: 512 blocks x 512 thr (8 waves), ALL resident (2 blocks/CU).
// Block owns 16 rows x ALL 32000 cols (NSPLIT=1): exactly 8192 row-streams
// device-wide, each written strictly left-to-right -> fill-kernel-shaped DRAM
// writes. Pass = 128 cols (8 tiles, 1 tile/wave), 250 passes.
#define PASSW  128
#define WT     (PASSW / 16)           // 8 tiles/pass = 1 per wave
#define PASSES (VOCAB / PASSW)        // 250
#define EPIPAD 8                      // epi row stride 136 f32

typedef __attribute__((ext_vector_type(8))) short short8;   // 8 bf16 = 4 VGPRs
typedef __attribute__((ext_vector_type(4))) float f32x4;    // MFMA accum

// ---------------------------------------------------------------------------
// Phase A: per-row attention/softmax/rec/self-gate, all f32, output gated bf16.
// One wave per batch row, 4 rows (4 waves) per block.  (proven, ~15 us)
// ---------------------------------------------------------------------------
__global__ __launch_bounds__(256) void phaseA_kernel(
    const float* __restrict__ x,            // [B, D]
    const float* __restrict__ attn_w,       // [D, P]
    const float* __restrict__ attn_b,       // [P]
    const float* __restrict__ pattern_dict, // [P, D]
    const float* __restrict__ self_w,       // [D, D]
    const float* __restrict__ self_b,       // [D]
    __hip_bfloat16* __restrict__ gated)     // [B, D] bf16 out
{
    __shared__ float xs[4][DIM];
    __shared__ float wls[4][NPAT];
    __shared__ float recs[4][DIM];

    const int lane = threadIdx.x & 63;
    const int wid  = threadIdx.x >> 6;
    const int row  = blockIdx.x * 4 + wid;

    xs[wid][lane]      = x[row * DIM + lane];
    xs[wid][lane + 64] = x[row * DIM + 64 + lane];
    __syncthreads();

    float acc = attn_b[lane];
#pragma unroll 8
    for (int d = 0; d < DIM; ++d)
        acc += xs[wid][d] * attn_w[d * NPAT + lane];

    float m = acc;
#pragma unroll
    for (int o = 32; o; o >>= 1) m = fmaxf(m, __shfl_xor(m, o));
    float e = expf(acc - m);
    float s = e;
#pragma unroll
    for (int o = 32; o; o >>= 1) s += __shfl_xor(s, o);
    float w = e / s;
    wls[wid][lane] = w;
    __syncthreads();

    float r0 = 0.f, r1 = 0.f;
#pragma unroll 8
    for (int p = 0; p < NPAT; ++p) {
        float wp = wls[wid][p];
        r0 += wp * pattern_dict[p * DIM + lane];
        r1 += wp * pattern_dict[p * DIM + 64 + lane];
    }
    recs[wid][lane]      = r0;
    recs[wid][lane + 64] = r1;
    __syncthreads();

    float s0 = self_b[lane], s1 = self_b[lane + 64];
#pragma unroll 8
    for (int k = 0; k < DIM; ++k) {
        float rk = recs[wid][k];
        s0 += rk * self_w[k * DIM + lane];
        s1 += rk * self_w[k * DIM + 64 + lane];
    }

    float p0 = s0 - r0, p1 = s1 - r1;
    float ss = p0 * p0 + p1 * p1;
#pragma unroll
    for (int o = 32; o; o >>= 1) ss += __shfl_xor(ss, o);
    float mag = sqrtf(ss);
    float g = 1.f / (1.f + expf(-mag));

    gated[row * DIM + lane]      = __float2bfloat16(r0 * g);
    gated[row * DIM + 64 + lane] = __float2bfloat16(r1 * g);
}

// ---------------------------------------------------------------------------
// Repack: out_w [D=128, V] f32 -> Bf fragment-major bf16 (proven R5-R7).
// Bf idx = ((tile*4 + ks)*64 + lane)*8 + j ; lane = kq*16 + r16 holds
// Bt[n = tile*16 + r16][k = ks*32 + kq*8 + j]. A pass's 8-tile window is a
// CONTIGUOUS 32768-B chunk -> linear global_load_lds staging.
// ---------------------------------------------------------------------------
__global__ __launch_bounds__(256) void repack_w_kernel(
    const float* __restrict__ out_w,        // [D, V]
    __hip_bfloat16* __restrict__ Bf)        // fragment-major [2000*4*64*8]
{
    __shared__ __hip_bfloat16 tile[64][136];

    const int t  = threadIdx.x;
    const int n0 = blockIdx.x * 64;
    const int c  = t & 63;
    const int k0 = t >> 6;

    for (int kk = 0; kk < DIM; kk += 4) {
        int k = kk + k0;
        tile[c][k] = __float2bfloat16(out_w[(size_t)k * VOCAB + n0 + c]);
    }
    __syncthreads();

    const int lane = t & 63;
    const int tl   = t >> 6;
    const int r16  = lane & 15;
    const int kq   = lane >> 4;
    const int gt   = (n0 >> 4) + tl;
#pragma unroll
    for (int ks = 0; ks < 4; ++ks) {
        uint4 v = *reinterpret_cast<const uint4*>(&tile[tl * 16 + r16][ks * 32 + kq * 8]);
        *reinterpret_cast<uint4*>(Bf + ((size_t)(gt * 4 + ks) * 64 + lane) * 8) = v;
    }
}

// ---------------------------------------------------------------------------
// GEMM: out = gated(bf16) @ Bt^T + bias, f32.
// 512 blocks x 8 waves; block = 16 rows x all cols, 250 passes of 128 cols.
// Per pass: stage next 32-KB Bf window into LDS dbuf (global_load_lds x4 per
// wave, contiguous); wave w computes tile w (4 ds_read_b128 + 4 MFMA, bias as
// C-in); acc -> epi LDS [16][136]; barrier (drains stage vmcnt + epi visible);
// each wave stores rows {2w, 2w+1} as ONE 1-KB instruction (2 x 512-B
// contiguous row-runs, strictly appending left-to-right per row); barrier.
// Writes: 8192 sequential row-streams total = fill-kernel-shaped.
// Reads: B window shared by all 8 waves; 512 x 8 MB = 4.3 GB L2 (~120 us,
// under the 154-us write floor); HBM B-refetch ~8 XCD x 8 MB.
// LDS 74.2 KB/block -> 2 blocks/CU: the other block's waves cover barrier
// bubbles. A-frags (16 VGPR) live in registers for the whole kernel.
// ---------------------------------------------------------------------------
__global__ __launch_bounds__(512, 4) void gemm_kernel(
    const __hip_bfloat16* __restrict__ A,   // gated [B, D]
    const __hip_bfloat16* __restrict__ Bf,  // fragment-major weights
    const float* __restrict__ bias,         // [V]
    float* __restrict__ out)                // [B, V]
{
    __shared__ __hip_bfloat16 bstage[2][PASSW * DIM];   // 2 x 32 KB
    __shared__ float epi[16][PASSW + EPIPAD];           // 8.5 KB

    const int lane = threadIdx.x & 63;
    const int w    = threadIdx.x >> 6;      // 0..7 = local tile index
    const int r16  = lane & 15;
    const int kq   = lane >> 4;             // 0..3
    const int row0 = blockIdx.x * 16;

    // A fragments for this block's 16 rows: registers for the whole kernel.
    short8 a[4];
#pragma unroll
    for (int ks = 0; ks < 4; ++ks)
        a[ks] = *reinterpret_cast<const short8*>(
            A + (size_t)(row0 + r16) * DIM + ks * 32 + kq * 8);

    // stage pass-p window (32768 B contiguous in Bf) into bstage[buf]:
    // wave w copies bytes [w*4096, (w+1)*4096) via 4 x 1-KB global_load_lds.
    auto stage = [&](int p, int buf) {
        const char* src = (const char*)Bf + (size_t)p * (PASSW * DIM * 2);
        char* dst = (char*)&bstage[buf][0];
#pragma unroll
        for (int i = 0; i < 4; ++i) {
            const int off = w * 4096 + i * 1024;
            __builtin_amdgcn_global_load_lds(
                (const void*)(src + off + lane * 16),
                (void*)(dst + off), 16, 0, 0);
        }
    };

    stage(0, 0);
    __syncthreads();

    int buf = 0;
    const int rr = lane >> 5;               // epi store: 0/1 (row within pair)
    const int cc = (lane & 31) * 4;         // epi store: col (f32)
    for (int p = 0; p < PASSES; ++p) {
        if (p + 1 < PASSES) stage(p + 1, buf ^ 1);   // overlap with compute

        // ---- compute tile w: cols p*128 + w*16 + [0,16) ----
        short8 b[4];
#pragma unroll
        for (int ks = 0; ks < 4; ++ks)
            b[ks] = *reinterpret_cast<const short8*>(
                &bstage[buf][((w * 4 + ks) * 64 + lane) * 8]);

        f32x4 acc = *reinterpret_cast<const f32x4*>(
            bias + p * PASSW + w * 16 + kq * 4);     // C-in = bias
#pragma unroll
        for (int ks = 0; ks < 4; ++ks)
            acc = __builtin_amdgcn_mfma_f32_16x16x32_bf16(b[ks], a[ks], acc, 0, 0, 0);

        // ---- transpose: lane holds row r16, cols w*16 + kq*4 + [0,4) ----
        *reinterpret_cast<f32x4*>(&epi[r16][w * 16 + kq * 4]) = acc;
        __syncthreads();   // epi visible; B-buf reads done; stage drained

        // ---- streaming store: wave w -> rows 2w, 2w+1; one 1-KB instr ----
        f32x4 v = *reinterpret_cast<const f32x4*>(&epi[2 * w + rr][cc]);
        *reinterpret_cast<f32x4*>(
            out + (size_t)(row0 + 2 * w + rr) * VOCAB + p * PASSW + cc) = v;
        __syncthreads();   // epi reads done before next pass overwrites
        buf ^= 1;
    }
}

// ---------------------------------------------------------------------------
extern "C" void kernel_launch(void* const* d_in, const int* in_sizes, int n_in,
                              void* d_out, int out_size, void* d_ws, size_t ws_size,
                              hipStream_t stream) {
    const float* x            = (const float*)d_in[0];
    const float* pattern_dict = (const float*)d_in[1];
    const float* attn_w       = (const float*)d_in[2];
    const float* attn_b       = (const float*)d_in[3];
    const float* self_w       = (const float*)d_in[4];
    const float* self_b       = (const float*)d_in[5];
    const float* out_w        = (const float*)d_in[6];
    const float* out_b        = (const float*)d_in[7];
    float* out = (float*)d_out;

    // workspace: gated bf16 [B,D] (2 MB) | Bf fragment-major bf16 (8.2 MB)
    __hip_bfloat16* gated = (__hip_bfloat16*)d_ws;
    __hip_bfloat16* Bf    = (__hip_bfloat16*)((char*)d_ws + (size_t)BATCH * DIM * 2);

    phaseA_kernel<<<BATCH / 4, 256, 0, stream>>>(
        x, attn_w, attn_b, pattern_dict, self_w, self_b, gated);
    repack_w_kernel<<<VOCAB / 64, 256, 0, stream>>>(out_w, Bf);
    gemm_kernel<<<BATCH / 16, 512, 0, stream>>>(gated, Bf, out_b, out);
}

// Round 9
// 386.802 us; speedup vs baseline: 1.2656x; 1.2656x over previous
//
#include <hip/hip_runtime.h>
#include <hip/hip_bf16.h>

// Sizes (fixed by the reference)
#define BATCH 8192
#define DIM   128
#define NPAT  64
#define VOCAB 32000

// GEMM geometry: 256 blocks x 512 thr (8 waves), 1 block/CU (130 KB LDS).
// Block = 64 rows x 16000 cols (NSPLIT=2). Pass = 128 cols, 125 passes,
// ONE barrier per pass. Stores via dbuf LDS transpose: full-line 512-B runs.
#define NSPLIT  2
#define SPLITW  (VOCAB / NSPLIT)      // 16000
#define PASSW   128                   // cols per pass (8 tiles)
#define PASSES  (SPLITW / PASSW)      // 125
#define RBLK    64                    // rows per block
#define MG      (BATCH / RBLK)        // 128 m-groups
#define EPIST   (PASSW + 4)           // epi row stride (f32), 16B-aligned

typedef __attribute__((ext_vector_type(8))) short short8;   // 8 bf16 = 4 VGPRs
typedef __attribute__((ext_vector_type(4))) float f32x4;    // MFMA accum

// ---------------------------------------------------------------------------
// Phase A: per-row attention/softmax/rec/self-gate, all f32, output gated bf16.
// One wave per batch row, 4 rows (4 waves) per block.  (proven, ~15 us)
// ---------------------------------------------------------------------------
__global__ __launch_bounds__(256) void phaseA_kernel(
    const float* __restrict__ x,            // [B, D]
    const float* __restrict__ attn_w,       // [D, P]
    const float* __restrict__ attn_b,       // [P]
    const float* __restrict__ pattern_dict, // [P, D]
    const float* __restrict__ self_w,       // [D, D]
    const float* __restrict__ self_b,       // [D]
    __hip_bfloat16* __restrict__ gated)     // [B, D] bf16 out
{
    __shared__ float xs[4][DIM];
    __shared__ float wls[4][NPAT];
    __shared__ float recs[4][DIM];

    const int lane = threadIdx.x & 63;
    const int wid  = threadIdx.x >> 6;
    const int row  = blockIdx.x * 4 + wid;

    xs[wid][lane]      = x[row * DIM + lane];
    xs[wid][lane + 64] = x[row * DIM + 64 + lane];
    __syncthreads();

    float acc = attn_b[lane];
#pragma unroll 8
    for (int d = 0; d < DIM; ++d)
        acc += xs[wid][d] * attn_w[d * NPAT + lane];

    float m = acc;
#pragma unroll
    for (int o = 32; o; o >>= 1) m = fmaxf(m, __shfl_xor(m, o));
    float e = expf(acc - m);
    float s = e;
#pragma unroll
    for (int o = 32; o; o >>= 1) s += __shfl_xor(s, o);
    float w = e / s;
    wls[wid][lane] = w;
    __syncthreads();

    float r0 = 0.f, r1 = 0.f;
#pragma unroll 8
    for (int p = 0; p < NPAT; ++p) {
        float wp = wls[wid][p];
        r0 += wp * pattern_dict[p * DIM + lane];
        r1 += wp * pattern_dict[p * DIM + 64 + lane];
    }
    recs[wid][lane]      = r0;
    recs[wid][lane + 64] = r1;
    __syncthreads();

    float s0 = self_b[lane], s1 = self_b[lane + 64];
#pragma unroll 8
    for (int k = 0; k < DIM; ++k) {
        float rk = recs[wid][k];
        s0 += rk * self_w[k * DIM + lane];
        s1 += rk * self_w[k * DIM + 64 + lane];
    }

    float p0 = s0 - r0, p1 = s1 - r1;
    float ss = p0 * p0 + p1 * p1;
#pragma unroll
    for (int o = 32; o; o >>= 1) ss += __shfl_xor(ss, o);
    float mag = sqrtf(ss);
    float g = 1.f / (1.f + expf(-mag));

    gated[row * DIM + lane]      = __float2bfloat16(r0 * g);
    gated[row * DIM + 64 + lane] = __float2bfloat16(r1 * g);
}

// ---------------------------------------------------------------------------
// Repack: out_w [D=128, V] f32 -> Bf fragment-major bf16 (proven R5-R8).
// Bf idx = ((tile*4 + ks)*64 + lane)*8 + j ; lane = kq*16 + r16 holds
// Bt[n = tile*16 + r16][k = ks*32 + kq*8 + j]. An 8-tile pass window is a
// CONTIGUOUS 32768-B chunk -> linear global_load_lds staging.
// ---------------------------------------------------------------------------
__global__ __launch_bounds__(256) void repack_w_kernel(
    const float* __restrict__ out_w,        // [D, V]
    __hip_bfloat16* __restrict__ Bf)        // fragment-major [2000*4*64*8]
{
    __shared__ __hip_bfloat16 tile[64][136];

    const int t  = threadIdx.x;
    const int n0 = blockIdx.x * 64;
    const int c  = t & 63;
    const int k0 = t >> 6;

    for (int kk = 0; kk < DIM; kk += 4) {
        int k = kk + k0;
        tile[c][k] = __float2bfloat16(out_w[(size_t)k * VOCAB + n0 + c]);
    }
    __syncthreads();

    const int lane = t & 63;
    const int tl   = t >> 6;
    const int r16  = lane & 15;
    const int kq   = lane >> 4;
    const int gt   = (n0 >> 4) + tl;
#pragma unroll
    for (int ks = 0; ks < 4; ++ks) {
        uint4 v = *reinterpret_cast<const uint4*>(&tile[tl * 16 + r16][ks * 32 + kq * 8]);
        *reinterpret_cast<uint4*>(Bf + ((size_t)(gt * 4 + ks) * 64 + lane) * 8) = v;
    }
}

// ---------------------------------------------------------------------------
// GEMM: out = gated(bf16) @ Bt^T + bias, f32.
// 256 blocks x 8 waves; block = 64 rows x 16000 cols; 125 passes of 128 cols;
// ONE barrier per pass. Per iteration p:
//   stage(p+1): 32-KB contiguous Bf window -> bstage[bb^1] (global_load_lds,
//               whole pass to complete, drained by the barrier)
//   store(p-1): from epi[ee^1] (written before last barrier): each wave
//               4 instrs x 2 rows x 512-B contiguous 128-B-aligned runs
//               (full-line write transactions; overlaps this pass's compute)
//   compute(p): wave w = (rowgroup rg=w>>1, tile-half th=w&1); 4 tiles
//               (th,th+2,th+4,th+6): 16 ds_read_b128 + 16 MFMA, bias as C-in;
//               acc -> epi[ee] (LDS transpose)
//   barrier; flip buffers.
// Writes: 16384 row-streams, strictly left-to-right, full-line instructions
// -> fill-kernel-shaped (R7's 64-B segments measured exactly half fill BW).
// Pass pacing = 32-KB store drain/block ~ 1.2 us -> write-floor-bound.
// LDS: 64 KB bstage + 66 KB epi = 130 KB -> 1 block/CU, grid 256 = all CUs.
// ---------------------------------------------------------------------------
__global__ __launch_bounds__(512, 2) void gemm_kernel(
    const __hip_bfloat16* __restrict__ A,   // gated [B, D]
    const __hip_bfloat16* __restrict__ Bf,  // fragment-major weights
    const float* __restrict__ bias,         // [V]
    float* __restrict__ out)                // [B, V]
{
    __shared__ __hip_bfloat16 bstage[2][PASSW * DIM];   // 2 x 32 KB
    __shared__ float epi[2][RBLK][EPIST];               // 2 x 33 KB

    const int lane = threadIdx.x & 63;
    const int w    = threadIdx.x >> 6;      // 0..7
    const int r16  = lane & 15;
    const int kq   = lane >> 4;             // 0..3
    const int mg   = blockIdx.x & (MG - 1);
    const int ns   = blockIdx.x >> 7;       // 0..1
    const int row0 = mg * RBLK;
    const int col0 = ns * SPLITW;
    const int rg   = w >> 1;                // rowgroup 0..3 (16 rows each)
    const int th   = w & 1;                 // tile half

    // A fragments for this wave's rowgroup: registers for the whole kernel.
    short8 a[4];
#pragma unroll
    for (int ks = 0; ks < 4; ++ks)
        a[ks] = *reinterpret_cast<const short8*>(
            A + (size_t)(row0 + rg * 16 + r16) * DIM + ks * 32 + kq * 8);

    // stage pass-p window (32768 B contiguous in Bf): wave w copies
    // [w*4096, (w+1)*4096) via 4 x 1-KB global_load_lds (16 B/lane).
    auto stage = [&](int p, int bufi) {
        const char* src = (const char*)Bf +
            (size_t)(ns * (SPLITW / 16) + p * (PASSW / 16)) * 4096;
        char* dst = (char*)&bstage[bufi][0];
#pragma unroll
        for (int i = 0; i < 4; ++i) {
            const int off = w * 4096 + i * 1024;
            __builtin_amdgcn_global_load_lds(
                (const void*)(src + off + lane * 16),
                (void*)(dst + off), 16, 0, 0);
        }
    };

    stage(0, 0);
    __syncthreads();

    const int sr = lane >> 5;               // store: row parity within pair
    const int sc = (lane & 31) * 4;         // store: col (f32) within pass
    int bb = 0, ee = 0;

    for (int p = 0; p < PASSES; ++p) {
        if (p + 1 < PASSES) stage(p + 1, bb ^ 1);

        // ---- store pass p-1 (epi[ee^1]) : overlaps this pass's compute ----
        if (p > 0) {
            const int colp = col0 + (p - 1) * PASSW;
#pragma unroll
            for (int i = 0; i < 4; ++i) {
                const int r = 8 * w + sr + 2 * i;
                f32x4 v = *reinterpret_cast<const f32x4*>(&epi[ee ^ 1][r][sc]);
                *reinterpret_cast<f32x4*>(
                    out + (size_t)(row0 + r) * VOCAB + colp + sc) = v;
            }
        }

        // ---- compute pass p: 4 tiles for this wave's rowgroup ----
        const int colp = col0 + p * PASSW;
#pragma unroll
        for (int j = 0; j < 4; ++j) {
            const int t = th + 2 * j;
            short8 b[4];
#pragma unroll
            for (int ks = 0; ks < 4; ++ks)
                b[ks] = *reinterpret_cast<const short8*>(
                    &bstage[bb][((t * 4 + ks) * 64 + lane) * 8]);

            f32x4 acc = *reinterpret_cast<const f32x4*>(
                bias + colp + t * 16 + kq * 4);          // C-in = bias
#pragma unroll
            for (int ks = 0; ks < 4; ++ks)
                acc = __builtin_amdgcn_mfma_f32_16x16x32_bf16(b[ks], a[ks], acc, 0, 0, 0);

            // transpose: lane holds row rg*16+r16, cols t*16 + kq*4 + [0,4)
            *reinterpret_cast<f32x4*>(&epi[ee][rg * 16 + r16][t * 16 + kq * 4]) = acc;
        }

        __syncthreads();   // epi[ee] visible; stage(p+1) drained; bstage[bb] free
        bb ^= 1; ee ^= 1;
    }

    // ---- final store: pass PASSES-1 from epi[ee^1] ----
    {
        const int colp = col0 + (PASSES - 1) * PASSW;
#pragma unroll
        for (int i = 0; i < 4; ++i) {
            const int r = 8 * w + sr + 2 * i;
            f32x4 v = *reinterpret_cast<const f32x4*>(&epi[ee ^ 1][r][sc]);
            *reinterpret_cast<f32x4*>(
                out + (size_t)(row0 + r) * VOCAB + colp + sc) = v;
        }
    }
}

// ---------------------------------------------------------------------------
extern "C" void kernel_launch(void* const* d_in, const int* in_sizes, int n_in,
                              void* d_out, int out_size, void* d_ws, size_t ws_size,
                              hipStream_t stream) {
    const float* x            = (const float*)d_in[0];
    const float* pattern_dict = (const float*)d_in[1];
    const float* attn_w       = (const float*)d_in[2];
    const float* attn_b       = (const float*)d_in[3];
    const float* self_w       = (const float*)d_in[4];
    const float* self_b       = (const float*)d_in[5];
    const float* out_w        = (const float*)d_in[6];
    const float* out_b        = (const float*)d_in[7];
    float* out = (float*)d_out;

    // workspace: gated bf16 [B,D] (2 MB) | Bf fragment-major bf16 (8.2 MB)
    __hip_bfloat16* gated = (__hip_bfloat16*)d_ws;
    __hip_bfloat16* Bf    = (__hip_bfloat16*)((char*)d_ws + (size_t)BATCH * DIM * 2);

    phaseA_kernel<<<BATCH / 4, 256, 0, stream>>>(
        x, attn_w, attn_b, pattern_dict, self_w, self_b, gated);
    repack_w_kernel<<<VOCAB / 64, 256, 0, stream>>>(out_w, Bf);
    gemm_kernel<<<MG * NSPLIT, 512, 0, stream>>>(gated, Bf, out_b, out);
}

// Round 10
// 268.304 us; speedup vs baseline: 1.8246x; 1.4417x over previous
//
#include <hip/hip_runtime.h>
#include <hip/hip_bf16.h>

// Sizes (fixed by the reference)
#define BATCH 8192
#define DIM   128
#define NPAT  64
#define VOCAB 32000
#define CHUNKS (BATCH / 16)   // 512 16-row A chunks

typedef __attribute__((ext_vector_type(8))) short short8;   // 8 bf16 = 4 VGPRs
typedef __attribute__((ext_vector_type(4))) float f32x4;    // MFMA accum

// ---------------------------------------------------------------------------
// Phase A: per-row attention/softmax/rec/self-gate, all f32, output gated bf16.
// One wave per batch row, 4 rows (4 waves) per block.  (proven, ~15 us)
// ---------------------------------------------------------------------------
__global__ __launch_bounds__(256) void phaseA_kernel(
    const float* __restrict__ x,            // [B, D]
    const float* __restrict__ attn_w,       // [D, P]
    const float* __restrict__ attn_b,       // [P]
    const float* __restrict__ pattern_dict, // [P, D]
    const float* __restrict__ self_w,       // [D, D]
    const float* __restrict__ self_b,       // [D]
    __hip_bfloat16* __restrict__ gated)     // [B, D] bf16 out
{
    __shared__ float xs[4][DIM];
    __shared__ float wls[4][NPAT];
    __shared__ float recs[4][DIM];

    const int lane = threadIdx.x & 63;
    const int wid  = threadIdx.x >> 6;
    const int row  = blockIdx.x * 4 + wid;

    xs[wid][lane]      = x[row * DIM + lane];
    xs[wid][lane + 64] = x[row * DIM + 64 + lane];
    __syncthreads();

    float acc = attn_b[lane];
#pragma unroll 8
    for (int d = 0; d < DIM; ++d)
        acc += xs[wid][d] * attn_w[d * NPAT + lane];

    float m = acc;
#pragma unroll
    for (int o = 32; o; o >>= 1) m = fmaxf(m, __shfl_xor(m, o));
    float e = expf(acc - m);
    float s = e;
#pragma unroll
    for (int o = 32; o; o >>= 1) s += __shfl_xor(s, o);
    float w = e / s;
    wls[wid][lane] = w;
    __syncthreads();

    float r0 = 0.f, r1 = 0.f;
#pragma unroll 8
    for (int p = 0; p < NPAT; ++p) {
        float wp = wls[wid][p];
        r0 += wp * pattern_dict[p * DIM + lane];
        r1 += wp * pattern_dict[p * DIM + 64 + lane];
    }
    recs[wid][lane]      = r0;
    recs[wid][lane + 64] = r1;
    __syncthreads();

    float s0 = self_b[lane], s1 = self_b[lane + 64];
#pragma unroll 8
    for (int k = 0; k < DIM; ++k) {
        float rk = recs[wid][k];
        s0 += rk * self_w[k * DIM + lane];
        s1 += rk * self_w[k * DIM + 64 + lane];
    }

    float p0 = s0 - r0, p1 = s1 - r1;
    float ss = p0 * p0 + p1 * p1;
#pragma unroll
    for (int o = 32; o; o >>= 1) ss += __shfl_xor(ss, o);
    float mag = sqrtf(ss);
    float g = 1.f / (1.f + expf(-mag));

    gated[row * DIM + lane]      = __float2bfloat16(r0 * g);
    gated[row * DIM + 64 + lane] = __float2bfloat16(r1 * g);
}

// ---------------------------------------------------------------------------
// Repack A: gated [B,D] bf16 -> Af fragment-major, 512 chunks x 4096 B.
// Af[((ch*4 + ks)*64 + lane)*8 + j] = gated[ch*16 + (lane&15)][ks*32 + (lane>>4)*8 + j]
// GEMM staging of one chunk = ONE contiguous 4-KB copy; ds_read conflict-free.
// ---------------------------------------------------------------------------
__global__ __launch_bounds__(256) void repack_a_kernel(
    const __hip_bfloat16* __restrict__ gated,
    __hip_bfloat16* __restrict__ Af)
{
    const int lane = threadIdx.x & 63;
    const int wv   = threadIdx.x >> 6;    // 0..3
    const int ch   = blockIdx.x * 4 + wv; // 0..511
    const int r16  = lane & 15;
    const int kq   = lane >> 4;
#pragma unroll
    for (int ks = 0; ks < 4; ++ks) {
        short8 v = *reinterpret_cast<const short8*>(
            gated + (size_t)(ch * 16 + r16) * DIM + ks * 32 + kq * 8);
        *reinterpret_cast<short8*>(
            Af + ((size_t)(ch * 4 + ks) * 64 + lane) * 8) = v;
    }
}

// ---------------------------------------------------------------------------
// Repack W: out_w [D=128, V] f32 -> Bf fragment-major bf16 (proven R5-R9).
// ---------------------------------------------------------------------------
__global__ __launch_bounds__(256) void repack_w_kernel(
    const float* __restrict__ out_w,        // [D, V]
    __hip_bfloat16* __restrict__ Bf)        // fragment-major [2000*4*64*8]
{
    __shared__ __hip_bfloat16 tile[64][136];

    const int t  = threadIdx.x;
    const int n0 = blockIdx.x * 64;
    const int c  = t & 63;
    const int k0 = t >> 6;

    for (int kk = 0; kk < DIM; kk += 4) {
        int k = kk + k0;
        tile[c][k] = __float2bfloat16(out_w[(size_t)k * VOCAB + n0 + c]);
    }
    __syncthreads();

    const int lane = t & 63;
    const int tl   = t >> 6;
    const int r16  = lane & 15;
    const int kq   = lane >> 4;
    const int gt   = (n0 >> 4) + tl;
#pragma unroll
    for (int ks = 0; ks < 4; ++ks) {
        uint4 v = *reinterpret_cast<const uint4*>(&tile[tl * 16 + r16][ks * 32 + kq * 8]);
        *reinterpret_cast<uint4*>(Bf + ((size_t)(gt * 4 + ks) * 64 + lane) * 8) = v;
    }
}

// ---------------------------------------------------------------------------
// GEMM, barrier-free: out = gated @ Bt^T + bias, f32.
// 500 blocks x 8 waves (2 blocks/CU, 64 KB LDS). Block owns a 64-col panel;
// B-frags for its 4 n-tiles are REGISTERS (64 VGPR), loaded once. Wave w
// independently sweeps chunks {w, w+8, ...} (64 iters x 16 rows), staging
// each 4-KB fragment-major A chunk into its PRIVATE LDS dbuf slice via
// global_load_lds (linear, contiguous) and self-pacing with s_waitcnt
// vmcnt(4) — NO __syncthreads anywhere. Per iter: 4 stage + 4 ds_read +
// 16 MFMA (bias as C-in) + epilogue.
// Epilogue reuses the just-consumed A buffer as a per-wave transpose pad
// (XOR-swizzled, bank-spread): acc -> LDS -> 4 store instructions, each
// covering 4 rows x 256-B contiguous 128-B-aligned full-line runs.
// Per-CU traffic: LDS ~8 MB, MFMA ~8 us, L2 A-refetch 2 MB/XCD-resident;
// the 1.048-GB output write stream is the only large HBM consumer.
// ---------------------------------------------------------------------------
__global__ __launch_bounds__(512, 4) void gemm_kernel(
    const __hip_bfloat16* __restrict__ Af,  // fragment-major A
    const __hip_bfloat16* __restrict__ Bf,  // fragment-major W
    const float* __restrict__ bias,         // [V]
    float* __restrict__ out)                // [B, V]
{
    __shared__ char lds[8][2][4096];        // per-wave private dbuf, 64 KB

    const int lane = threadIdx.x & 63;
    const int w    = threadIdx.x >> 6;      // 0..7
    const int r16  = lane & 15;
    const int kq   = lane >> 4;             // 0..3
    const int hi   = lane >> 4;
    const int lo   = lane & 15;
    const int col0 = blockIdx.x * 64;
    const int t0   = blockIdx.x * 4;        // first n-tile

    // B fragments for this block's 4 tiles: registers for the whole kernel.
    short8 b[4][4];
#pragma unroll
    for (int t = 0; t < 4; ++t)
#pragma unroll
        for (int ks = 0; ks < 4; ++ks)
            b[t][ks] = *reinterpret_cast<const short8*>(
                Bf + ((size_t)((t0 + t) * 4 + ks) * 64 + lane) * 8);

    // bias as MFMA C-in (D row = n = kq*4 + reg)
    f32x4 bv[4];
#pragma unroll
    for (int t = 0; t < 4; ++t)
        bv[t] = *reinterpret_cast<const f32x4*>(bias + col0 + t * 16 + kq * 4);

    char* buf0 = &lds[w][0][0];
    char* buf1 = &lds[w][1][0];

    auto stage = [&](int ch, char* dst) {
        const char* src = (const char*)Af + (size_t)ch * 4096 + lane * 16;
#pragma unroll
        for (int i = 0; i < 4; ++i)
            __builtin_amdgcn_global_load_lds((const void*)(src + i * 1024),
                                             (void*)(dst + i * 1024), 16, 0, 0);
    };

    stage(w, buf0);   // prologue: first chunk

#pragma unroll 2
    for (int c = 0; c < 64; ++c) {
        char* cur = (c & 1) ? buf1 : buf0;
        char* nxt = (c & 1) ? buf0 : buf1;
        const int ch = w + c * 8;

        // epi reads of 'nxt' (previous iter's pad) must finish before DMA
        asm volatile("s_waitcnt lgkmcnt(0)" ::: "memory");
        if (c + 1 < 64) stage(ch + 8, nxt);
        // drain: current chunk's stage (and old stores); keep next stage in flight
        asm volatile("s_waitcnt vmcnt(4)" ::: "memory");
        __builtin_amdgcn_sched_barrier(0);

        short8 a[4];
#pragma unroll
        for (int ks = 0; ks < 4; ++ks)
            a[ks] = *reinterpret_cast<const short8*>(cur + ks * 1024 + lane * 16);

        f32x4 acc[4];
#pragma unroll
        for (int t = 0; t < 4; ++t) {
            acc[t] = bv[t];
#pragma unroll
            for (int ks = 0; ks < 4; ++ks)
                acc[t] = __builtin_amdgcn_mfma_f32_16x16x32_bf16(
                    b[t][ks], a[ks], acc[t], 0, 0, 0);
        }

        // ---- per-wave epilogue transpose in 'cur' (A consumed), swizzled ----
        // logical: row r16 (local), col-bytes t*64 + kq*16; phys ^= (row&7)<<4
#pragma unroll
        for (int t = 0; t < 4; ++t) {
            const int pb = r16 * 256 + ((t * 64 + kq * 16) ^ ((r16 & 7) << 4));
            *reinterpret_cast<f32x4*>(cur + pb) = acc[t];
        }
        // read back full rows, store 4 rows x 256-B contiguous per instruction
        const size_t orow0 = (size_t)ch * 16 * VOCAB + col0;
#pragma unroll
        for (int s = 0; s < 4; ++s) {
            const int row = s * 4 + hi;
            const int pb  = row * 256 + ((lo * 16) ^ ((row & 7) << 4));
            f32x4 v = *reinterpret_cast<const f32x4*>(cur + pb);
            *reinterpret_cast<f32x4*>(out + orow0 + (size_t)row * VOCAB + lo * 4) = v;
        }
    }
}

// ---------------------------------------------------------------------------
extern "C" void kernel_launch(void* const* d_in, const int* in_sizes, int n_in,
                              void* d_out, int out_size, void* d_ws, size_t ws_size,
                              hipStream_t stream) {
    const float* x            = (const float*)d_in[0];
    const float* pattern_dict = (const float*)d_in[1];
    const float* attn_w       = (const float*)d_in[2];
    const float* attn_b       = (const float*)d_in[3];
    const float* self_w       = (const float*)d_in[4];
    const float* self_b       = (const float*)d_in[5];
    const float* out_w        = (const float*)d_in[6];
    const float* out_b        = (const float*)d_in[7];
    float* out = (float*)d_out;

    // ws: gated 2 MB | Af 2 MB | Bf 8.2 MB
    __hip_bfloat16* gated = (__hip_bfloat16*)d_ws;
    __hip_bfloat16* Af    = (__hip_bfloat16*)((char*)d_ws + (size_t)BATCH * DIM * 2);
    __hip_bfloat16* Bf    = (__hip_bfloat16*)((char*)d_ws + (size_t)2 * BATCH * DIM * 2);

    phaseA_kernel<<<BATCH / 4, 256, 0, stream>>>(
        x, attn_w, attn_b, pattern_dict, self_w, self_b, gated);
    repack_a_kernel<<<CHUNKS / 4, 256, 0, stream>>>(gated, Af);
    repack_w_kernel<<<VOCAB / 64, 256, 0, stream>>>(out_w, Bf);
    gemm_kernel<<<VOCAB / 64, 512, 0, stream>>>(Af, Bf, out_b, out);
}